// Round 5
// baseline (199.116 us; speedup 1.0000x reference)
//
#include <hip/hip_runtime.h>
#include <stdint.h>

#define NFR 256
#define HW 196
#define CH 512
#define EPS_POS 0.65f
#define EPS_NEG 0.40f
#define INV_TAU (1.0f/0.03f)
#define TEMP 0.07f

typedef __bf16 bf16x8 __attribute__((ext_vector_type(8)));
typedef float f32x4 __attribute__((ext_vector_type(4)));
typedef unsigned short u16x8 __attribute__((ext_vector_type(8)));

__device__ __forceinline__ float sigmoidf_(float x) {
  return 1.0f / (1.0f + __expf(-x));
}

// round-to-nearest-even f32 -> bf16 bits (inputs finite)
__device__ __forceinline__ unsigned short f2bf(float x) {
  unsigned int u = __float_as_uint(x);
  unsigned int r = u + 0x7FFFu + ((u >> 16) & 1u);
  return (unsigned short)(r >> 16);
}

// ---------------- K1: audio L2-normalize -> bf16 [256][512]; also zero accums --
__global__ __launch_bounds__(64) void audio_norm_k(const float* __restrict__ audio,
                                                   unsigned short* __restrict__ abf,
                                                   float* __restrict__ numbase,   // num..den contiguous
                                                   float* __restrict__ negbase) { // negnum..negden contiguous
  const int r = blockIdx.x;
  const int l = threadIdx.x;
  {
    const int idx = r * 64 + l;
    f32x4 z = {0.f, 0.f, 0.f, 0.f};
    f32x4* p = (f32x4*)numbase;
    p[idx * 2] = z;
    p[idx * 2 + 1] = z;
    if (r < 2) ((f32x4*)negbase)[r * 64 + l] = z;   // 512 floats
  }
  const float4* src = reinterpret_cast<const float4*>(audio + (size_t)r * CH);
  float4 a = src[l];
  float4 b = src[64 + l];
  float ss = a.x*a.x + a.y*a.y + a.z*a.z + a.w*a.w
           + b.x*b.x + b.y*b.y + b.z*b.z + b.w*b.w;
#pragma unroll
  for (int m = 1; m < 64; m <<= 1) ss += __shfl_xor(ss, m);
  float sc = rsqrtf(ss);
  ushort4 o;
  o.x = f2bf(a.x*sc); o.y = f2bf(a.y*sc); o.z = f2bf(a.z*sc); o.w = f2bf(a.w*sc);
  reinterpret_cast<ushort4*>(abf + (size_t)r * CH)[l] = o;
  o.x = f2bf(b.x*sc); o.y = f2bf(b.y*sc); o.z = f2bf(b.z*sc); o.w = f2bf(b.w*sc);
  reinterpret_cast<ushort4*>(abf + (size_t)r * CH)[64 + l] = o;
}

// ---------------- K2: FUSED frame-normalize + GEMM (50176 x 256 x 512) --------
// 784 blocks x 64 rows. 4 waves; wave w owns output cols [64w, 64w+64).
// Phase 1: raw f32 rows read once -> row-normalize -> bf16 -> LDS Afull[64][512]
//   (XOR-swizzled 16B granules: phys g = g ^ (row&7)).  ONE barrier total.
// K-loop: A frags from LDS (conflict-free b128), B frags DIRECT from global/L2
//   into registers (1-deep prefetch) -- no __syncthreads in the loop.
__global__ __launch_bounds__(256, 2) void simk(const float* __restrict__ frame,
                                               const unsigned short* __restrict__ abf,
                                               float* __restrict__ num, float* __restrict__ den,
                                               float* __restrict__ negnum, float* __restrict__ negden) {
  __shared__ unsigned short Afull[64][512];   // 64 KB -> 2 blocks/CU
  const int tid = threadIdx.x;
  const int l = tid & 63, w = tid >> 6;
  const int m0 = blockIdx.x * 64;

  // B-frag base: lane l -> col 64w+(l&15), k-offset (l>>4)*8
  const unsigned short* abB = abf + (size_t)(64 * w + (l & 15)) * CH + (l >> 4) * 8;

  // early prefetch of B(t=0): completes during phase 1 (drained at the barrier)
  bf16x8 bnext[4];
#pragma unroll
  for (int j = 0; j < 4; ++j)
    bnext[j] = *reinterpret_cast<const bf16x8*>(abB + (size_t)(16 * j) * CH);

  // ---- Phase 1: normalize rows 16w..16w+15 into Afull ----
  {
    const int l8 = l * 8;
#pragma unroll 2
    for (int rr = 0; rr < 16; ++rr) {
      const int r = 16 * w + rr;
      const float4* src = reinterpret_cast<const float4*>(frame + (size_t)(m0 + r) * CH + l8);
      float4 a = src[0];
      float4 b = src[1];
      float ss = a.x*a.x + a.y*a.y + a.z*a.z + a.w*a.w
               + b.x*b.x + b.y*b.y + b.z*b.z + b.w*b.w;
#pragma unroll
      for (int m = 1; m < 64; m <<= 1) ss += __shfl_xor(ss, m);
      const float sc = rsqrtf(ss);
      u16x8 o;
      o[0] = f2bf(a.x*sc); o[1] = f2bf(a.y*sc); o[2] = f2bf(a.z*sc); o[3] = f2bf(a.w*sc);
      o[4] = f2bf(b.x*sc); o[5] = f2bf(b.y*sc); o[6] = f2bf(b.z*sc); o[7] = f2bf(b.w*sc);
      char* dst = (char*)&Afull[0][0] + r * 1024 + ((l ^ (r & 7)) << 4);
      *reinterpret_cast<u16x8*>(dst) = o;
    }
  }
  __syncthreads();   // the ONLY barrier: Afull visible to all waves

  f32x4 acc[4][4] = {};
  const int aRowByte = (l & 15) * 1024;

  for (int t = 0; t < 16; ++t) {
    bf16x8 bcur[4];
#pragma unroll
    for (int j = 0; j < 4; ++j) bcur[j] = bnext[j];
    if (t < 15) {
      const unsigned short* bp = abB + (t + 1) * 32;
#pragma unroll
      for (int j = 0; j < 4; ++j)
        bnext[j] = *reinterpret_cast<const bf16x8*>(bp + (size_t)(16 * j) * CH);
    }
    // A granule: logical g = 4t + (l>>4), physical g ^ (l&7) (row&7 == l&7)
    const int gA = (((4 * t + (l >> 4)) ^ (l & 7)) << 4);
    const char* Ab = (const char*)&Afull[0][0] + aRowByte + gA;
    bf16x8 af[4];
#pragma unroll
    for (int i = 0; i < 4; ++i)
      af[i] = *reinterpret_cast<const bf16x8*>(Ab + 16384 * i);   // +16 rows
#pragma unroll
    for (int i = 0; i < 4; ++i)
#pragma unroll
      for (int j = 0; j < 4; ++j)
        acc[i][j] = __builtin_amdgcn_mfma_f32_16x16x32_bf16(af[i], bcur[j], acc[i][j], 0, 0, 0);
  }

  // ---- epilogue: C layout col=lane&15, row=(lane>>4)*4+jj  [m89-verified] ----
  const int rg = l >> 4;
  const int colL = l & 15;
  const int nlo = m0 / HW;
  const int nhi = (m0 + 63) / HW;

  float cn0[4] = {}, cd0[4] = {}, cn1[4] = {}, cd1[4] = {};
  float gn0 = 0.f, gd0 = 0.f, gn1 = 0.f, gd1 = 0.f;
#pragma unroll
  for (int i = 0; i < 4; ++i) {
#pragma unroll
    for (int jj = 0; jj < 4; ++jj) {
      const int P = m0 + i * 16 + rg * 4 + jj;
      const int nrow = P / HW;
      const bool lo = (nrow == nlo);
#pragma unroll
      for (int j = 0; j < 4; ++j) {
        const float s = acc[i][j][jj];
        const float wp = sigmoidf_((s - EPS_POS) * INV_TAU);
        const float wps = wp * s;
        if (lo) { cn0[j] += wps; cd0[j] += wp; }
        else    { cn1[j] += wps; cd1[j] += wp; }
        const int kglob = w * 64 + j * 16 + colL;
        if (kglob == nrow) {
          const float wneg = 1.f - sigmoidf_((s - EPS_NEG) * INV_TAU);
          if (lo) { gn0 += wneg * s; gd0 += wneg; }
          else    { gn1 += wneg * s; gd1 += wneg; }
        }
      }
    }
  }
  if (gd0 > 0.f) { atomicAdd(&negnum[nlo], gn0); atomicAdd(&negden[nlo], gd0); }
  if (gd1 > 0.f) { atomicAdd(&negnum[nhi], gn1); atomicAdd(&negden[nhi], gd1); }

#pragma unroll
  for (int j = 0; j < 4; ++j) {
    float v0 = cn0[j], d0 = cd0[j], v1 = cn1[j], d1 = cd1[j];
    v0 += __shfl_xor(v0, 16); v0 += __shfl_xor(v0, 32);
    d0 += __shfl_xor(d0, 16); d0 += __shfl_xor(d0, 32);
    v1 += __shfl_xor(v1, 16); v1 += __shfl_xor(v1, 32);
    d1 += __shfl_xor(d1, 16); d1 += __shfl_xor(d1, 32);
    if (rg == 0) {
      const int kglob = w * 64 + j * 16 + colL;
      atomicAdd(&num[nlo * NFR + kglob], v0);
      atomicAdd(&den[nlo * NFR + kglob], d0);
      if (nhi != nlo) {
        atomicAdd(&num[nhi * NFR + kglob], v1);
        atomicAdd(&den[nhi * NFR + kglob], d1);
      }
    }
  }
}

// ---------------- K3: per-row stats (also zeroes out for loss_k) ----------------
__global__ __launch_bounds__(64) void rowstats_k(const float* __restrict__ num,
                                                 const float* __restrict__ den,
                                                 const float* __restrict__ negnum,
                                                 const float* __restrict__ negden,
                                                 float* __restrict__ Pi_d,
                                                 float* __restrict__ Ni_d,
                                                 float* __restrict__ out) {
  const int r = blockIdx.x;
  const int l = threadIdx.x;
  if (r == 0 && l == 0) out[0] = 0.f;
  float vsum = 0.f, pvac = 0.f;
#pragma unroll
  for (int cb = 0; cb < 4; ++cb) {
    const int k = cb * 64 + l;
    const float ratio = num[r * NFR + k] / den[r * NFR + k];
    vsum += ratio;
    if (k == r) pvac = ratio;
  }
#pragma unroll
  for (int m = 1; m < 64; m <<= 1) {
    vsum += __shfl_xor(vsum, m);
    pvac += __shfl_xor(pvac, m);
  }
  if (l == 0) {
    const float nh = negnum[r] / negden[r];
    Pi_d[r] = TEMP * pvac;
    Ni_d[r] = TEMP * (nh + vsum - 100.f * pvac);   // masked easy-sum
  }
}

// ---------------- K4: loss = (1/N) sum_{i,j} softplus(Ni_d[j]-Pi_d[i]) ---------
__global__ __launch_bounds__(256) void loss_k(const float* __restrict__ Pi_d,
                                              const float* __restrict__ Ni_d,
                                              float* __restrict__ out) {
  __shared__ float red[4];
  const int i = blockIdx.x;
  const int tid = threadIdx.x;
  const int l = tid & 63, w = tid >> 6;
  const float x = Ni_d[tid] - Pi_d[i];
  const float m = fmaxf(x, 0.f);
  float sp = m + __logf(__expf(x - m) + __expf(-m));
#pragma unroll
  for (int s2 = 1; s2 < 64; s2 <<= 1) sp += __shfl_xor(sp, s2);
  if (l == 0) red[w] = sp;
  __syncthreads();
  if (tid == 0) atomicAdd(out, (red[0] + red[1] + red[2] + red[3]) * (1.0f / (float)NFR));
}

extern "C" void kernel_launch(void* const* d_in, const int* in_sizes, int n_in,
                              void* d_out, int out_size, void* d_ws, size_t ws_size,
                              hipStream_t stream) {
  const float* frame = (const float*)d_in[0];   // (256,14,14,512) f32
  const float* audio = (const float*)d_in[1];   // (256,512) f32
  float* out = (float*)d_out;                   // scalar f32

  char* ws = (char*)d_ws;
  unsigned short* abf = (unsigned short*)ws;        // 256 KB
  float* num    = (float*)(ws + 262144);            // num,den,negnum,negden contiguous
  float* den    = num + NFR * NFR;
  float* negnum = den + NFR * NFR;
  float* negden = negnum + NFR;
  float* Pi_d   = negden + NFR;
  float* Ni_d   = Pi_d + NFR;

  audio_norm_k<<<256, 64, 0, stream>>>(audio, abf, num, negnum);
  simk<<<784, 256, 0, stream>>>(frame, abf, num, den, negnum, negden);
  rowstats_k<<<256, 64, 0, stream>>>(num, den, negnum, negden, Pi_d, Ni_d, out);
  loss_k<<<256, 256, 0, stream>>>(Pi_d, Ni_d, out);
}

// Round 7
// 181.903 us; speedup vs baseline: 1.0946x; 1.0946x over previous
//
#include <hip/hip_runtime.h>
#include <stdint.h>

#define NFR 256
#define HW 196
#define CH 512
#define EPS_POS 0.65f
#define EPS_NEG 0.40f
#define INV_TAU (1.0f/0.03f)
#define TEMP 0.07f

typedef __bf16 bf16x8 __attribute__((ext_vector_type(8)));
typedef float f32x4 __attribute__((ext_vector_type(4)));
typedef unsigned short u16x8 __attribute__((ext_vector_type(8)));

__device__ __forceinline__ float sigmoidf_(float x) {
  return 1.0f / (1.0f + __expf(-x));
}

// round-to-nearest-even f32 -> bf16 bits (inputs finite)
__device__ __forceinline__ unsigned short f2bf(float x) {
  unsigned int u = __float_as_uint(x);
  unsigned int r = u + 0x7FFFu + ((u >> 16) & 1u);
  return (unsigned short)(r >> 16);
}

// ---------------- K1: audio L2-normalize -> bf16 [256][512]; also zero accums --
__global__ __launch_bounds__(64) void audio_norm_k(const float* __restrict__ audio,
                                                   unsigned short* __restrict__ abf,
                                                   float* __restrict__ numbase,   // num..den contiguous
                                                   float* __restrict__ negbase) { // negnum..negden contiguous
  const int r = blockIdx.x;
  const int l = threadIdx.x;
  {
    const int idx = r * 64 + l;
    f32x4 z = {0.f, 0.f, 0.f, 0.f};
    f32x4* p = (f32x4*)numbase;
    p[idx * 2] = z;
    p[idx * 2 + 1] = z;
    if (r < 2) ((f32x4*)negbase)[r * 64 + l] = z;   // 512 floats
  }
  const float4* src = reinterpret_cast<const float4*>(audio + (size_t)r * CH);
  float4 a = src[l];
  float4 b = src[64 + l];
  float ss = a.x*a.x + a.y*a.y + a.z*a.z + a.w*a.w
           + b.x*b.x + b.y*b.y + b.z*b.z + b.w*b.w;
#pragma unroll
  for (int m = 1; m < 64; m <<= 1) ss += __shfl_xor(ss, m);
  float sc = rsqrtf(ss);
  ushort4 o;
  o.x = f2bf(a.x*sc); o.y = f2bf(a.y*sc); o.z = f2bf(a.z*sc); o.w = f2bf(a.w*sc);
  reinterpret_cast<ushort4*>(abf + (size_t)r * CH)[l] = o;
  o.x = f2bf(b.x*sc); o.y = f2bf(b.y*sc); o.z = f2bf(b.z*sc); o.w = f2bf(b.w*sc);
  reinterpret_cast<ushort4*>(abf + (size_t)r * CH)[64 + l] = o;
}

// ---------------- K1b: repack abf into MFMA B-fragment order -------------------
// packed[((t*16 + c)*64 + l)*8 + e] = abf[16c + (l&15)][t*32 + (l>>4)*8 + e]
// In simk, wave w / frag j / step t reads chunk (t*16 + w*4 + j) at lane l:
// a contiguous, fully-coalesced 1 KB load.
__global__ __launch_bounds__(64) void repack_k(const unsigned short* __restrict__ abf,
                                               unsigned short* __restrict__ packed) {
  const int chunk = blockIdx.x;        // 0..255 = t*16 + c
  const int t = chunk >> 4, c = chunk & 15;
  const int l = threadIdx.x;
  const u16x8 v = *reinterpret_cast<const u16x8*>(
      abf + (size_t)(16 * c + (l & 15)) * CH + t * 32 + (l >> 4) * 8);
  *reinterpret_cast<u16x8*>(packed + ((size_t)chunk * 64 + l) * 8) = v;
}

// ---------------- K2: FUSED frame-normalize + GEMM (50176 x 256 x 512) --------
// 1568 blocks x 32 rows. 256 thr = 4 waves; wave w owns cols [64w, 64w+64).
// LDS 32 KB -> 4 blocks/CU -> 4 waves/SIMD (latency hiding).
// Phase 1: raw f32 rows (coalesced 32B/lane) -> normalize -> bf16 -> LDS
//   (XOR-swizzled 16B granules, bank-balanced). ONE barrier.
// K-loop: A from LDS (2 b128 reads), B from packed (4 coalesced 1KB loads,
//   1-deep prefetch), 8 MFMA per step. No barriers in loop.
__global__ __launch_bounds__(256, 4) void simk(const float* __restrict__ frame,
                                               const unsigned short* __restrict__ packed,
                                               float* __restrict__ num, float* __restrict__ den,
                                               float* __restrict__ negnum, float* __restrict__ negden) {
  __shared__ unsigned short Afull[32][512];   // 32 KB
  const int tid = threadIdx.x;
  const int l = tid & 63, w = tid >> 6;
  const int m0 = blockIdx.x * 32;

  // B: chunk (t*16 + w*4 + j), elem offset l*8 within chunk (512 elems/chunk)
  const unsigned short* pb = packed + (size_t)w * 2048 + l * 8;

  // prefetch B(t=0)
  bf16x8 bnext[4];
#pragma unroll
  for (int j = 0; j < 4; ++j)
    bnext[j] = *reinterpret_cast<const bf16x8*>(pb + j * 512);

  // ---- Phase 1: normalize rows 8w..8w+7 into Afull ----
  {
    const int l8 = l * 8;
#pragma unroll 2
    for (int rr = 0; rr < 8; ++rr) {
      const int r = 8 * w + rr;
      const float4* src = reinterpret_cast<const float4*>(frame + (size_t)(m0 + r) * CH + l8);
      float4 a = src[0];
      float4 b = src[1];
      float ss = a.x*a.x + a.y*a.y + a.z*a.z + a.w*a.w
               + b.x*b.x + b.y*b.y + b.z*b.z + b.w*b.w;
#pragma unroll
      for (int m = 1; m < 64; m <<= 1) ss += __shfl_xor(ss, m);
      const float sc = rsqrtf(ss);
      u16x8 o;
      o[0] = f2bf(a.x*sc); o[1] = f2bf(a.y*sc); o[2] = f2bf(a.z*sc); o[3] = f2bf(a.w*sc);
      o[4] = f2bf(b.x*sc); o[5] = f2bf(b.y*sc); o[6] = f2bf(b.z*sc); o[7] = f2bf(b.w*sc);
      char* dst = (char*)&Afull[0][0] + r * 1024 + ((l ^ (r & 7)) << 4);
      *reinterpret_cast<u16x8*>(dst) = o;
    }
  }
  __syncthreads();   // the ONLY barrier

  f32x4 acc[2][4] = {};
  const int aRowByte = (l & 15) * 1024;

  for (int t = 0; t < 16; ++t) {
    bf16x8 bcur[4];
#pragma unroll
    for (int j = 0; j < 4; ++j) bcur[j] = bnext[j];
    if (t < 15) {
      const unsigned short* bp = pb + (t + 1) * 8192;
#pragma unroll
      for (int j = 0; j < 4; ++j)
        bnext[j] = *reinterpret_cast<const bf16x8*>(bp + j * 512);
    }
    // A granule: logical g = 4t + (l>>4), physical g ^ (row&7) (row&7 == l&7)
    const int gA = (((4 * t + (l >> 4)) ^ (l & 7)) << 4);
    const char* Ab = (const char*)&Afull[0][0] + aRowByte + gA;
    bf16x8 af[2];
#pragma unroll
    for (int i = 0; i < 2; ++i)
      af[i] = *reinterpret_cast<const bf16x8*>(Ab + 16384 * i);   // +16 rows
#pragma unroll
    for (int i = 0; i < 2; ++i)
#pragma unroll
      for (int j = 0; j < 4; ++j)
        acc[i][j] = __builtin_amdgcn_mfma_f32_16x16x32_bf16(af[i], bcur[j], acc[i][j], 0, 0, 0);
  }

  // ---- epilogue: C layout col=lane&15, row=(lane>>4)*4+jj  [m89-verified] ----
  const int rg = l >> 4;
  const int colL = l & 15;
  const int nlo = m0 / HW;
  const int nhi = (m0 + 31) / HW;

  float cn0[4] = {}, cd0[4] = {}, cn1[4] = {}, cd1[4] = {};
  float gn0 = 0.f, gd0 = 0.f, gn1 = 0.f, gd1 = 0.f;
#pragma unroll
  for (int i = 0; i < 2; ++i) {
#pragma unroll
    for (int jj = 0; jj < 4; ++jj) {
      const int P = m0 + i * 16 + rg * 4 + jj;
      const int nrow = P / HW;
      const bool lo = (nrow == nlo);
#pragma unroll
      for (int j = 0; j < 4; ++j) {
        const float s = acc[i][j][jj];
        const float wp = sigmoidf_((s - EPS_POS) * INV_TAU);
        const float wps = wp * s;
        if (lo) { cn0[j] += wps; cd0[j] += wp; }
        else    { cn1[j] += wps; cd1[j] += wp; }
        const int kglob = w * 64 + j * 16 + colL;
        if (kglob == nrow) {
          const float wneg = 1.f - sigmoidf_((s - EPS_NEG) * INV_TAU);
          if (lo) { gn0 += wneg * s; gd0 += wneg; }
          else    { gn1 += wneg * s; gd1 += wneg; }
        }
      }
    }
  }
  if (gd0 > 0.f) { atomicAdd(&negnum[nlo], gn0); atomicAdd(&negden[nlo], gd0); }
  if (gd1 > 0.f) { atomicAdd(&negnum[nhi], gn1); atomicAdd(&negden[nhi], gd1); }

#pragma unroll
  for (int j = 0; j < 4; ++j) {
    float v0 = cn0[j], d0 = cd0[j], v1 = cn1[j], d1 = cd1[j];
    v0 += __shfl_xor(v0, 16); v0 += __shfl_xor(v0, 32);
    d0 += __shfl_xor(d0, 16); d0 += __shfl_xor(d0, 32);
    v1 += __shfl_xor(v1, 16); v1 += __shfl_xor(v1, 32);
    d1 += __shfl_xor(d1, 16); d1 += __shfl_xor(d1, 32);
    if (rg == 0) {
      const int kglob = w * 64 + j * 16 + colL;
      atomicAdd(&num[nlo * NFR + kglob], v0);
      atomicAdd(&den[nlo * NFR + kglob], d0);
      if (nhi != nlo) {
        atomicAdd(&num[nhi * NFR + kglob], v1);
        atomicAdd(&den[nhi * NFR + kglob], d1);
      }
    }
  }
}

// ---------------- K3: per-row stats (also zeroes out for loss_k) ----------------
__global__ __launch_bounds__(64) void rowstats_k(const float* __restrict__ num,
                                                 const float* __restrict__ den,
                                                 const float* __restrict__ negnum,
                                                 const float* __restrict__ negden,
                                                 float* __restrict__ Pi_d,
                                                 float* __restrict__ Ni_d,
                                                 float* __restrict__ out) {
  const int r = blockIdx.x;
  const int l = threadIdx.x;
  if (r == 0 && l == 0) out[0] = 0.f;
  float vsum = 0.f, pvac = 0.f;
#pragma unroll
  for (int cb = 0; cb < 4; ++cb) {
    const int k = cb * 64 + l;
    const float ratio = num[r * NFR + k] / den[r * NFR + k];
    vsum += ratio;
    if (k == r) pvac = ratio;
  }
#pragma unroll
  for (int m = 1; m < 64; m <<= 1) {
    vsum += __shfl_xor(vsum, m);
    pvac += __shfl_xor(pvac, m);
  }
  if (l == 0) {
    const float nh = negnum[r] / negden[r];
    Pi_d[r] = TEMP * pvac;
    Ni_d[r] = TEMP * (nh + vsum - 100.f * pvac);   // masked easy-sum
  }
}

// ---------------- K4: loss = (1/N) sum_{i,j} softplus(Ni_d[j]-Pi_d[i]) ---------
__global__ __launch_bounds__(256) void loss_k(const float* __restrict__ Pi_d,
                                              const float* __restrict__ Ni_d,
                                              float* __restrict__ out) {
  __shared__ float red[4];
  const int i = blockIdx.x;
  const int tid = threadIdx.x;
  const int l = tid & 63, w = tid >> 6;
  const float x = Ni_d[tid] - Pi_d[i];
  const float m = fmaxf(x, 0.f);
  float sp = m + __logf(__expf(x - m) + __expf(-m));
#pragma unroll
  for (int s2 = 1; s2 < 64; s2 <<= 1) sp += __shfl_xor(sp, s2);
  if (l == 0) red[w] = sp;
  __syncthreads();
  if (tid == 0) atomicAdd(out, (red[0] + red[1] + red[2] + red[3]) * (1.0f / (float)NFR));
}

extern "C" void kernel_launch(void* const* d_in, const int* in_sizes, int n_in,
                              void* d_out, int out_size, void* d_ws, size_t ws_size,
                              hipStream_t stream) {
  const float* frame = (const float*)d_in[0];   // (256,14,14,512) f32
  const float* audio = (const float*)d_in[1];   // (256,512) f32
  float* out = (float*)d_out;                   // scalar f32

  char* ws = (char*)d_ws;
  unsigned short* abf    = (unsigned short*)ws;                  // 256 KB
  unsigned short* packed = (unsigned short*)(ws + 262144);       // 256 KB
  float* num    = (float*)(ws + 524288);        // num,den,negnum,negden contiguous
  float* den    = num + NFR * NFR;
  float* negnum = den + NFR * NFR;
  float* negden = negnum + NFR;
  float* Pi_d   = negden + NFR;
  float* Ni_d   = Pi_d + NFR;

  audio_norm_k<<<256, 64, 0, stream>>>(audio, abf, num, negnum);
  repack_k<<<256, 64, 0, stream>>>(abf, packed);
  simk<<<1568, 256, 0, stream>>>(frame, packed, num, den, negnum, negden);
  rowstats_k<<<256, 64, 0, stream>>>(num, den, negnum, negden, Pi_d, Ni_d, out);
  loss_k<<<256, 256, 0, stream>>>(Pi_d, Ni_d, out);
}